// Round 1
// baseline (135.844 us; speedup 1.0000x reference)
//
#include <hip/hip_runtime.h>
#include <math.h>

// ---------------------------------------------------------------------------
// Points splat: out[h,w,c] = sigmoid(4 * sum_p relu(1 - dist_p(y,x)) * wc[p,c])
// dist_p(y,x) = |(y-ly, x-lx) @ T_p|^2, T_p = matrix_offsets + I*scale,
// scale = sqrt(P)/2 * exp(msfo).
// Strategy (round 0 baseline): expand dist to quadratic coefficients per point
// (kernel 1, P threads), then brute-force per-pixel loop over all P points
// reading coefficients from LDS broadcast (kernel 2).
// ---------------------------------------------------------------------------

__global__ void points_precompute(const float* __restrict__ loc,     // (P,2) y,x
                                  const float* __restrict__ moff,    // (P,2,2)
                                  const float* __restrict__ msfo,    // (P,)
                                  const float* __restrict__ colors,  // (P,3)
                                  const float* __restrict__ alphas,  // (P,)
                                  float* __restrict__ coef,          // (P,12)
                                  int P) {
    int p = blockIdx.x * blockDim.x + threadIdx.x;
    if (p >= P) return;
    float ly = loc[2 * p + 0];
    float lx = loc[2 * p + 1];
    float m00 = moff[4 * p + 0], m01 = moff[4 * p + 1];
    float m10 = moff[4 * p + 2], m11 = moff[4 * p + 3];
    float s = 0.5f * sqrtf((float)P) * expf(msfo[p]);
    float T00 = m00 + s, T01 = m01;
    float T10 = m10,     T11 = m11 + s;
    // t0 = T00*y + T10*x + u2 ; t1 = T01*y + T11*x + v2
    float u0 = T00, u1 = T10, u2 = -(T00 * ly + T10 * lx);
    float v0 = T01, v1 = T11, v2 = -(T01 * ly + T11 * lx);
    // dist = A*y^2 + B*x^2 + C*xy + D*y + E*x + F
    float A = u0 * u0 + v0 * v0;
    float B = u1 * u1 + v1 * v1;
    float C = 2.f * (u0 * u1 + v0 * v1);
    float D = 2.f * (u0 * u2 + v0 * v2);
    float E = 2.f * (u1 * u2 + v1 * v2);
    float F = u2 * u2 + v2 * v2;
    float al = alphas[p];
    float w0 = colors[3 * p + 0] * al;
    float w1 = colors[3 * p + 1] * al;
    float w2 = colors[3 * p + 2] * al;
    float* o = coef + 12 * p;
    o[0] = A; o[1] = B; o[2]  = C; o[3]  = D;
    o[4] = E; o[5] = F; o[6]  = w0; o[7] = w1;
    o[8] = w2; o[9] = 0.f; o[10] = 0.f; o[11] = 0.f;
}

__global__ void points_render(const int* __restrict__ Hp,
                              const int* __restrict__ Wp,
                              const float* __restrict__ coef,  // (P,12)
                              float* __restrict__ out,         // (H,W,3)
                              int P) {
    extern __shared__ float sc[];  // P*12 floats
    const int n = 12 * P;
    for (int i = threadIdx.x * 4; i < n; i += blockDim.x * 4) {
        *(float4*)(sc + i) = *(const float4*)(coef + i);
    }
    __syncthreads();

    const int H = *Hp, W = *Wp;
    const int pix = blockIdx.x * blockDim.x + threadIdx.x;
    if (pix >= H * W) return;
    const int h = pix / W;
    const int w = pix - h * W;
    const float ratio = (float)W / (float)H;
    const float y = -1.f + 2.f * (float)h / (float)(H - 1);
    const float x = ratio * (-1.f + 2.f * (float)w / (float)(W - 1));
    const float y2 = y * y, x2 = x * x, xy = x * y;

    float a0 = 0.f, a1 = 0.f, a2 = 0.f;
#pragma unroll 4
    for (int p = 0; p < P; ++p) {
        const float4 c0 = *(const float4*)(sc + 12 * p);      // A,B,C,D
        const float4 c1 = *(const float4*)(sc + 12 * p + 4);  // E,F,w0,w1
        const float  w2v = sc[12 * p + 8];                    // w2
        float dist = fmaf(c0.x, y2,
                     fmaf(c0.y, x2,
                     fmaf(c0.z, xy,
                     fmaf(c0.w, y,
                     fmaf(c1.x, x, c1.y)))));
        float m = fmaxf(0.f, 1.f - dist);
        a0 = fmaf(m, c1.z, a0);
        a1 = fmaf(m, c1.w, a1);
        a2 = fmaf(m, w2v, a2);
    }
    out[3 * pix + 0] = 1.f / (1.f + __expf(-4.f * a0));
    out[3 * pix + 1] = 1.f / (1.f + __expf(-4.f * a1));
    out[3 * pix + 2] = 1.f / (1.f + __expf(-4.f * a2));
}

extern "C" void kernel_launch(void* const* d_in, const int* in_sizes, int n_in,
                              void* d_out, int out_size, void* d_ws, size_t ws_size,
                              hipStream_t stream) {
    const int*   Hp     = (const int*)d_in[0];
    const int*   Wp     = (const int*)d_in[1];
    const float* loc    = (const float*)d_in[2];  // (1,1,P,2)
    const float* moff   = (const float*)d_in[3];  // (P,2,2)
    const float* msfo   = (const float*)d_in[4];  // (P,1,1)
    const float* colors = (const float*)d_in[5];  // (1,1,P,3)
    const float* alphas = (const float*)d_in[6];  // (1,1,P,1)
    float* out = (float*)d_out;
    float* coef = (float*)d_ws;

    const int P = in_sizes[3] / 4;       // matrix_offsets has P*2*2 elements
    const int total_pix = out_size / 3;  // H*W

    points_precompute<<<(P + 255) / 256, 256, 0, stream>>>(
        loc, moff, msfo, colors, alphas, coef, P);

    const int block = 256;
    const int grid = (total_pix + block - 1) / block;
    const size_t lds = (size_t)P * 12 * sizeof(float);
    points_render<<<grid, block, lds, stream>>>(Hp, Wp, coef, out, P);
}

// Round 2
// 100.862 us; speedup vs baseline: 1.3468x; 1.3468x over previous
//
#include <hip/hip_runtime.h>
#include <hip/hip_fp16.h>
#include <math.h>

// ---------------------------------------------------------------------------
// Fused points splat. Per block: build per-point quadratic coefficients into
// LDS (redundantly per block, ~2us), then each thread renders 4 same-row
// pixels reading 8 packed floats/point (2x ds_read_b128, wave-uniform
// broadcast).
//
// dist = A y^2 + B x^2 + C xy + D y + E x + F;  m = max(0, G - y*s1 - x*u)
// with G = 1-F, s1 = A y + D, u = B x + C y + E.  w1,w2 packed as f16 pair
// so all 9 per-point values fit 8 floats -> 2 LDS instrs/point (was 3).
// Round-1 evidence: LDS-pipe-bound (3 instr/pt, 16 waves/CU -> 78us).
// ---------------------------------------------------------------------------

__global__ __launch_bounds__(256) void points_fused(
        const int* __restrict__ Hp, const int* __restrict__ Wp,
        const float* __restrict__ loc,     // (P,2) y,x
        const float* __restrict__ moff,    // (P,2,2)
        const float* __restrict__ msfo,    // (P,)
        const float* __restrict__ colors,  // (P,3)
        const float* __restrict__ alphas,  // (P,)
        float* __restrict__ out,           // (H,W,3)
        int P, int total_pix) {
    extern __shared__ float sc[];  // P*8 floats

    // ---- build coefficient table (every block, cooperatively) ----
    for (int p = threadIdx.x; p < P; p += blockDim.x) {
        float ly = loc[2 * p + 0], lx = loc[2 * p + 1];
        float m00 = moff[4 * p + 0], m01 = moff[4 * p + 1];
        float m10 = moff[4 * p + 2], m11 = moff[4 * p + 3];
        float s = 0.5f * sqrtf((float)P) * expf(msfo[p]);
        float T00 = m00 + s, T01 = m01;
        float T10 = m10,     T11 = m11 + s;
        float u2 = -(T00 * ly + T10 * lx);
        float v2 = -(T01 * ly + T11 * lx);
        float A = T00 * T00 + T01 * T01;
        float B = T10 * T10 + T11 * T11;
        float C = 2.f * (T00 * T10 + T01 * T11);
        float D = 2.f * (T00 * u2 + T01 * v2);
        float E = 2.f * (T10 * u2 + T11 * v2);
        float F = u2 * u2 + v2 * v2;
        float G = 1.f - F;
        float al = alphas[p];
        float w0 = colors[3 * p + 0] * al;
        float w1 = colors[3 * p + 1] * al;
        float w2 = colors[3 * p + 2] * al;
        unsigned int bits = ((unsigned int)__half_as_ushort(__float2half_rn(w2)) << 16)
                          |  (unsigned int)__half_as_ushort(__float2half_rn(w1));
        float* o = sc + 8 * p;
        o[0] = A; o[1] = B; o[2] = C; o[3] = D;
        o[4] = E; o[5] = G; o[6] = w0; o[7] = __uint_as_float(bits);
    }
    __syncthreads();

    const int H = *Hp, W = *Wp;
    const int g = blockIdx.x * blockDim.x + threadIdx.x;
    const int px0 = g * 4;
    if (px0 >= total_pix) return;

    const float ratio = (float)W / (float)H;
    const float sx = 2.f * ratio / (float)(W - 1);
    const int h0 = px0 / W;
    const int c0 = px0 - h0 * W;

    const float4* sc4 = (const float4*)sc;
    float a00 = 0.f, a01 = 0.f, a02 = 0.f;
    float a10 = 0.f, a11 = 0.f, a12 = 0.f;
    float a20 = 0.f, a21 = 0.f, a22 = 0.f;
    float a30 = 0.f, a31 = 0.f, a32 = 0.f;

    if (c0 + 3 < W && px0 + 3 < total_pix) {
        // fast path: 4 pixels share the row (always taken when W%4==0)
        const float y  = -1.f + 2.f * (float)h0 / (float)(H - 1);
        const float x0 = -ratio + sx * (float)c0;
        const float x1 = x0 + sx, x2 = x0 + 2.f * sx, x3 = x0 + 3.f * sx;

#pragma unroll 4
        for (int p = 0; p < P; ++p) {
            const float4 q0 = sc4[2 * p];      // A,B,C,D
            const float4 q1 = sc4[2 * p + 1];  // E,G,w0,pack(w1,w2)
            const float s1 = fmaf(q0.x, y, q0.w);   // A y + D
            const float s2 = fmaf(-y, s1, q1.y);    // G - y*s1
            const float s3 = fmaf(q0.z, y, q1.x);   // C y + E
            const unsigned int bits = __float_as_uint(q1.w);
            const float w0v = q1.z;
            const float w1v = __half2float(__ushort_as_half((unsigned short)(bits & 0xffffu)));
            const float w2v = __half2float(__ushort_as_half((unsigned short)(bits >> 16)));

            float u, m;
            u = fmaf(q0.y, x0, s3); m = fmaxf(fmaf(-x0, u, s2), 0.f);
            a00 = fmaf(m, w0v, a00); a01 = fmaf(m, w1v, a01); a02 = fmaf(m, w2v, a02);
            u = fmaf(q0.y, x1, s3); m = fmaxf(fmaf(-x1, u, s2), 0.f);
            a10 = fmaf(m, w0v, a10); a11 = fmaf(m, w1v, a11); a12 = fmaf(m, w2v, a12);
            u = fmaf(q0.y, x2, s3); m = fmaxf(fmaf(-x2, u, s2), 0.f);
            a20 = fmaf(m, w0v, a20); a21 = fmaf(m, w1v, a21); a22 = fmaf(m, w2v, a22);
            u = fmaf(q0.y, x3, s3); m = fmaxf(fmaf(-x3, u, s2), 0.f);
            a30 = fmaf(m, w0v, a30); a31 = fmaf(m, w1v, a31); a32 = fmaf(m, w2v, a32);
        }

        float4 r0, r1, r2;
        r0.x = 1.f / (1.f + __expf(-4.f * a00));
        r0.y = 1.f / (1.f + __expf(-4.f * a01));
        r0.z = 1.f / (1.f + __expf(-4.f * a02));
        r0.w = 1.f / (1.f + __expf(-4.f * a10));
        r1.x = 1.f / (1.f + __expf(-4.f * a11));
        r1.y = 1.f / (1.f + __expf(-4.f * a12));
        r1.z = 1.f / (1.f + __expf(-4.f * a20));
        r1.w = 1.f / (1.f + __expf(-4.f * a21));
        r2.x = 1.f / (1.f + __expf(-4.f * a22));
        r2.y = 1.f / (1.f + __expf(-4.f * a30));
        r2.z = 1.f / (1.f + __expf(-4.f * a31));
        r2.w = 1.f / (1.f + __expf(-4.f * a32));
        float4* op = (float4*)(out + (size_t)3 * px0);  // 48*g bytes: 16B aligned
        op[0] = r0; op[1] = r1; op[2] = r2;
    } else {
        // generic fallback (row crossing / tail) — per-pixel
        for (int j = 0; j < 4; ++j) {
            int px = px0 + j;
            if (px >= total_pix) break;
            int h = px / W, c = px - h * W;
            float y = -1.f + 2.f * (float)h / (float)(H - 1);
            float x = -ratio + sx * (float)c;
            float b0 = 0.f, b1 = 0.f, b2 = 0.f;
            for (int p = 0; p < P; ++p) {
                const float4 q0 = sc4[2 * p];
                const float4 q1 = sc4[2 * p + 1];
                float s1 = fmaf(q0.x, y, q0.w);
                float s2 = fmaf(-y, s1, q1.y);
                float s3 = fmaf(q0.z, y, q1.x);
                unsigned int bits = __float_as_uint(q1.w);
                float u = fmaf(q0.y, x, s3);
                float m = fmaxf(fmaf(-x, u, s2), 0.f);
                b0 = fmaf(m, q1.z, b0);
                b1 = fmaf(m, __half2float(__ushort_as_half((unsigned short)(bits & 0xffffu))), b1);
                b2 = fmaf(m, __half2float(__ushort_as_half((unsigned short)(bits >> 16))), b2);
            }
            out[3 * px + 0] = 1.f / (1.f + __expf(-4.f * b0));
            out[3 * px + 1] = 1.f / (1.f + __expf(-4.f * b1));
            out[3 * px + 2] = 1.f / (1.f + __expf(-4.f * b2));
        }
    }
}

extern "C" void kernel_launch(void* const* d_in, const int* in_sizes, int n_in,
                              void* d_out, int out_size, void* d_ws, size_t ws_size,
                              hipStream_t stream) {
    const int*   Hp     = (const int*)d_in[0];
    const int*   Wp     = (const int*)d_in[1];
    const float* loc    = (const float*)d_in[2];  // (1,1,P,2)
    const float* moff   = (const float*)d_in[3];  // (P,2,2)
    const float* msfo   = (const float*)d_in[4];  // (P,1,1)
    const float* colors = (const float*)d_in[5];  // (1,1,P,3)
    const float* alphas = (const float*)d_in[6];  // (1,1,P,1)
    float* out = (float*)d_out;

    const int P = in_sizes[3] / 4;       // matrix_offsets: P*2*2 elements
    const int total_pix = out_size / 3;  // H*W

    const int block = 256;
    const int px_per_block = block * 4;
    const int grid = (total_pix + px_per_block - 1) / px_per_block;
    const size_t lds = (size_t)P * 8 * sizeof(float);
    points_fused<<<grid, block, lds, stream>>>(
        Hp, Wp, loc, moff, msfo, colors, alphas, out, P, total_pix);
}

// Round 3
// 79.469 us; speedup vs baseline: 1.7094x; 1.2692x over previous
//
#include <hip/hip_runtime.h>
#include <hip/hip_fp16.h>
#include <math.h>

// ---------------------------------------------------------------------------
// Tile-culled points splat (round 3).
// Evidence (r2): brute-force loop over all P=512 points is ~43us and
// LDS/VALU-bound, but each point's support ellipse (dist<1) has radius
// ~25px -> avg ~4 points actually cover a pixel. So: persistent blocks over
// 16x16-px tiles; per tile each block recomputes per-point quadratic coefs
// (cheap, 2 pts/thread), tests the point's exact conservative bbox
// (dy=sqrt(B/det), dx=sqrt(A/det)) against the tile, compacts survivors into
// LDS via atomic counter (~10/tile), then renders 1 px/thread over the short
// list. Degenerate det -> infinite bbox -> point always kept (correct for
// any input). Fixed ~57us harness overhead observed constant across rounds;
// only dispatch time is in play.
// ---------------------------------------------------------------------------

__global__ __launch_bounds__(256) void points_tiled(
        const int* __restrict__ Hp, const int* __restrict__ Wp,
        const float* __restrict__ loc,     // (P,2) y,x
        const float* __restrict__ moff,    // (P,2,2)
        const float* __restrict__ msfo,    // (P,)
        const float* __restrict__ colors,  // (P,3)
        const float* __restrict__ alphas,  // (P,)
        float* __restrict__ out,           // (H,W,3)
        int P) {
    extern __shared__ float sPts[];  // P*8 floats (worst case: all points hit)
    __shared__ int scnt;

    const int H = *Hp, W = *Wp;
    const float ratio = (float)W / (float)H;
    const float sy = 2.f / (float)(H - 1);
    const float sx = 2.f * ratio / (float)(W - 1);
    const int tilesX = (W + 15) >> 4;
    const int tilesY = (H + 15) >> 4;
    const int numTiles = tilesX * tilesY;
    const float sP = 0.5f * sqrtf((float)P);

    for (int t = blockIdx.x; t < numTiles; t += gridDim.x) {
        if (threadIdx.x == 0) scnt = 0;
        __syncthreads();

        const int r0 = (t / tilesX) << 4;
        const int c0 = (t - (t / tilesX) * tilesX) << 4;
        const int r1 = min(r0 + 15, H - 1);
        const int c1 = min(c0 + 15, W - 1);
        const float ty0 = -1.f + sy * (float)r0;
        const float ty1 = -1.f + sy * (float)r1;
        const float tx0 = -ratio + sx * (float)c0;
        const float tx1 = -ratio + sx * (float)c1;

        // ---- cull + compact: 2 points/thread for P=512 ----
        for (int p = threadIdx.x; p < P; p += blockDim.x) {
            const float ly = loc[2 * p + 0], lx = loc[2 * p + 1];
            const float m00 = moff[4 * p + 0], m01 = moff[4 * p + 1];
            const float m10 = moff[4 * p + 2], m11 = moff[4 * p + 3];
            const float s = sP * __expf(msfo[p]);
            const float T00 = m00 + s, T01 = m01;
            const float T10 = m10,     T11 = m11 + s;
            const float A  = T00 * T00 + T01 * T01;
            const float B  = T10 * T10 + T11 * T11;
            const float Ch = T00 * T10 + T01 * T11;  // C/2
            const float det = A * B - Ch * Ch;
            const float inv = (det > 1e-20f) ? 1.f / det : 1e30f;
            const float dy = sqrtf(B * inv) + 1e-4f;
            const float dx = sqrtf(A * inv) + 1e-4f;
            const bool hit = (ly + dy >= ty0) && (ly - dy <= ty1) &&
                             (lx + dx >= tx0) && (lx - dx <= tx1);
            if (hit) {
                const float u2 = -(T00 * ly + T10 * lx);
                const float v2 = -(T01 * ly + T11 * lx);
                const float C = 2.f * Ch;
                const float D = 2.f * (T00 * u2 + T01 * v2);
                const float E = 2.f * (T10 * u2 + T11 * v2);
                const float F = u2 * u2 + v2 * v2;
                const float G = 1.f - F;
                const float al = alphas[p];
                const float w0 = colors[3 * p + 0] * al;
                const float w1 = colors[3 * p + 1] * al;
                const float w2 = colors[3 * p + 2] * al;
                const unsigned bits =
                    (((unsigned)__half_as_ushort(__float2half_rn(w2))) << 16) |
                     (unsigned)__half_as_ushort(__float2half_rn(w1));
                const int slot = atomicAdd(&scnt, 1);
                float4* o = (float4*)(sPts + 8 * slot);
                o[0] = make_float4(A, B, C, D);
                o[1] = make_float4(E, G, w0, __uint_as_float(bits));
            }
        }
        __syncthreads();

        // ---- render: 1 px/thread over compacted list ----
        const int n = scnt;
        const int row = r0 + (threadIdx.x >> 4);
        const int col = c0 + (threadIdx.x & 15);
        if (row < H && col < W) {
            const float y = -1.f + sy * (float)row;
            const float x = -ratio + sx * (float)col;
            float a0 = 0.f, a1 = 0.f, a2 = 0.f;
            const float4* sc4 = (const float4*)sPts;
            for (int i = 0; i < n; ++i) {
                const float4 q0 = sc4[2 * i];      // A,B,C,D
                const float4 q1 = sc4[2 * i + 1];  // E,G,w0,pack(w1,w2)
                const float s1 = fmaf(q0.x, y, q0.w);   // A y + D
                const float s2 = fmaf(-y, s1, q1.y);    // G - y*s1
                float u = fmaf(q0.z, y, q1.x);          // C y + E
                u = fmaf(q0.y, x, u);                   // + B x
                const float m = fmaxf(fmaf(-x, u, s2), 0.f);
                const unsigned bits = __float_as_uint(q1.w);
                a0 = fmaf(m, q1.z, a0);
                a1 = fmaf(m, __half2float(__ushort_as_half((unsigned short)(bits & 0xffffu))), a1);
                a2 = fmaf(m, __half2float(__ushort_as_half((unsigned short)(bits >> 16))), a2);
            }
            float* o = out + 3 * ((size_t)row * W + col);
            o[0] = 1.f / (1.f + __expf(-4.f * a0));
            o[1] = 1.f / (1.f + __expf(-4.f * a1));
            o[2] = 1.f / (1.f + __expf(-4.f * a2));
        }
        __syncthreads();  // protect sPts/scnt before next tile iteration
    }
}

extern "C" void kernel_launch(void* const* d_in, const int* in_sizes, int n_in,
                              void* d_out, int out_size, void* d_ws, size_t ws_size,
                              hipStream_t stream) {
    const int*   Hp     = (const int*)d_in[0];
    const int*   Wp     = (const int*)d_in[1];
    const float* loc    = (const float*)d_in[2];  // (1,1,P,2)
    const float* moff   = (const float*)d_in[3];  // (P,2,2)
    const float* msfo   = (const float*)d_in[4];  // (P,1,1)
    const float* colors = (const float*)d_in[5];  // (1,1,P,3)
    const float* alphas = (const float*)d_in[6];  // (1,1,P,1)
    float* out = (float*)d_out;

    const int P = in_sizes[3] / 4;       // matrix_offsets: P*2*2 elements
    const int total_pix = out_size / 3;  // H*W

    const int block = 256;
    // one block per 256 pixels ~= one 16x16 tile; persistent loop covers any
    // H,W (incl. non-multiples of 16 where numTiles > grid)
    const int grid = (total_pix + block - 1) / block;
    const size_t lds = (size_t)P * 8 * sizeof(float);
    points_tiled<<<grid, block, lds, stream>>>(
        Hp, Wp, loc, moff, msfo, colors, alphas, out, P);
}

// Round 4
// 78.671 us; speedup vs baseline: 1.7267x; 1.0101x over previous
//
#include <hip/hip_runtime.h>
#include <hip/hip_fp16.h>
#include <math.h>

// ---------------------------------------------------------------------------
// Two-phase tile-culled points splat (round 4).
// r3 evidence: per-tile redundant coefficient recompute (512 pts x 1024
// blocks, transcendentals + scattered loads + serial dep chains) left the
// render kernel at ~22us. Fix: prep kernel computes per-point coefs (8 f32)
// + conservative bbox (float4) ONCE into d_ws; tile kernel culls with one
// coalesced float4 load + 4 compares per point, compacts ~10 winners' coefs
// into LDS, renders 1px/thread. Harness overhead (~57us: 40us d_ws 268MB
// re-poison fill + ~17us fills/restores/launch) is fixed and untouchable.
// ---------------------------------------------------------------------------

__global__ __launch_bounds__(256) void points_prep(
        const float* __restrict__ loc,     // (P,2) y,x
        const float* __restrict__ moff,    // (P,2,2)
        const float* __restrict__ msfo,    // (P,)
        const float* __restrict__ colors,  // (P,3)
        const float* __restrict__ alphas,  // (P,)
        float* __restrict__ coef,          // (P,8)
        float4* __restrict__ bbox,         // (P): ylo,yhi,xlo,xhi
        int P) {
    int p = blockIdx.x * blockDim.x + threadIdx.x;
    if (p >= P) return;
    const float ly = loc[2 * p + 0], lx = loc[2 * p + 1];
    const float m00 = moff[4 * p + 0], m01 = moff[4 * p + 1];
    const float m10 = moff[4 * p + 2], m11 = moff[4 * p + 3];
    const float s = 0.5f * sqrtf((float)P) * expf(msfo[p]);
    const float T00 = m00 + s, T01 = m01;
    const float T10 = m10,     T11 = m11 + s;
    const float A  = T00 * T00 + T01 * T01;
    const float B  = T10 * T10 + T11 * T11;
    const float Ch = T00 * T10 + T01 * T11;  // C/2
    const float det = A * B - Ch * Ch;
    const float inv = (det > 1e-20f) ? 1.f / det : 1e30f;
    const float dy = sqrtf(B * inv) + 1e-4f;
    const float dx = sqrtf(A * inv) + 1e-4f;
    const float u2 = -(T00 * ly + T10 * lx);
    const float v2 = -(T01 * ly + T11 * lx);
    const float C = 2.f * Ch;
    const float D = 2.f * (T00 * u2 + T01 * v2);
    const float E = 2.f * (T10 * u2 + T11 * v2);
    const float F = u2 * u2 + v2 * v2;
    const float G = 1.f - F;
    const float al = alphas[p];
    const float w0 = colors[3 * p + 0] * al;
    const float w1 = colors[3 * p + 1] * al;
    const float w2 = colors[3 * p + 2] * al;
    const unsigned bits =
        (((unsigned)__half_as_ushort(__float2half_rn(w2))) << 16) |
         (unsigned)__half_as_ushort(__float2half_rn(w1));
    float4* o = (float4*)(coef + 8 * p);
    o[0] = make_float4(A, B, C, D);
    o[1] = make_float4(E, G, w0, __uint_as_float(bits));
    bbox[p] = make_float4(ly - dy, ly + dy, lx - dx, lx + dx);
}

__global__ __launch_bounds__(256) void points_tiled(
        const int* __restrict__ Hp, const int* __restrict__ Wp,
        const float* __restrict__ coef,   // (P,8)
        const float4* __restrict__ bbox,  // (P)
        float* __restrict__ out,          // (H,W,3)
        int P) {
    extern __shared__ float sPts[];  // P*8 floats worst case
    __shared__ int scnt;

    const int H = *Hp, W = *Wp;
    const float ratio = (float)W / (float)H;
    const float sy = 2.f / (float)max(H - 1, 1);
    const float sx = 2.f * ratio / (float)max(W - 1, 1);
    const int tilesX = (W + 15) >> 4;
    const int tilesY = (H + 15) >> 4;
    const int numTiles = tilesX * tilesY;

    for (int t = blockIdx.x; t < numTiles; t += gridDim.x) {
        if (threadIdx.x == 0) scnt = 0;
        __syncthreads();

        const int tr = t / tilesX;
        const int r0 = tr << 4;
        const int c0 = (t - tr * tilesX) << 4;
        const float ty0 = -1.f + sy * (float)r0;
        const float ty1 = -1.f + sy * (float)min(r0 + 15, H - 1);
        const float tx0 = -ratio + sx * (float)c0;
        const float tx1 = -ratio + sx * (float)min(c0 + 15, W - 1);

        // ---- cull: coalesced bbox load + 4 compares; compact hit coefs ----
        for (int p = threadIdx.x; p < P; p += blockDim.x) {
            const float4 bb = bbox[p];  // ylo,yhi,xlo,xhi
            const bool hit = (bb.y >= ty0) && (bb.x <= ty1) &&
                             (bb.w >= tx0) && (bb.z <= tx1);
            if (hit) {
                const int slot = atomicAdd(&scnt, 1);
                const float4* src = (const float4*)(coef + 8 * p);
                float4* dst = (float4*)(sPts + 8 * slot);
                dst[0] = src[0];
                dst[1] = src[1];
            }
        }
        __syncthreads();

        // ---- render: 1 px/thread over compacted list ----
        const int n = scnt;
        const int row = r0 + (threadIdx.x >> 4);
        const int col = c0 + (threadIdx.x & 15);
        if (row < H && col < W) {
            const float y = -1.f + sy * (float)row;
            const float x = -ratio + sx * (float)col;
            float a0 = 0.f, a1 = 0.f, a2 = 0.f;
            const float4* sc4 = (const float4*)sPts;
            for (int i = 0; i < n; ++i) {
                const float4 q0 = sc4[2 * i];      // A,B,C,D
                const float4 q1 = sc4[2 * i + 1];  // E,G,w0,pack(w1,w2)
                const float s1 = fmaf(q0.x, y, q0.w);   // A y + D
                const float s2 = fmaf(-y, s1, q1.y);    // G - y*s1
                float u = fmaf(q0.z, y, q1.x);          // C y + E
                u = fmaf(q0.y, x, u);                   // + B x
                const float m = fmaxf(fmaf(-x, u, s2), 0.f);
                const unsigned bits = __float_as_uint(q1.w);
                a0 = fmaf(m, q1.z, a0);
                a1 = fmaf(m, __half2float(__ushort_as_half((unsigned short)(bits & 0xffffu))), a1);
                a2 = fmaf(m, __half2float(__ushort_as_half((unsigned short)(bits >> 16))), a2);
            }
            float* o = out + 3 * ((size_t)row * W + col);
            o[0] = 1.f / (1.f + __expf(-4.f * a0));
            o[1] = 1.f / (1.f + __expf(-4.f * a1));
            o[2] = 1.f / (1.f + __expf(-4.f * a2));
        }
        __syncthreads();  // protect sPts/scnt before next tile
    }
}

extern "C" void kernel_launch(void* const* d_in, const int* in_sizes, int n_in,
                              void* d_out, int out_size, void* d_ws, size_t ws_size,
                              hipStream_t stream) {
    const int*   Hp     = (const int*)d_in[0];
    const int*   Wp     = (const int*)d_in[1];
    const float* loc    = (const float*)d_in[2];  // (1,1,P,2)
    const float* moff   = (const float*)d_in[3];  // (P,2,2)
    const float* msfo   = (const float*)d_in[4];  // (P,1,1)
    const float* colors = (const float*)d_in[5];  // (1,1,P,3)
    const float* alphas = (const float*)d_in[6];  // (1,1,P,1)
    float* out = (float*)d_out;

    const int P = in_sizes[3] / 4;       // matrix_offsets: P*2*2 elements
    const int total_pix = out_size / 3;  // H*W

    float*  coef = (float*)d_ws;                    // P*8 floats
    float4* bbox = (float4*)((char*)d_ws + (size_t)P * 8 * sizeof(float));

    points_prep<<<(P + 255) / 256, 256, 0, stream>>>(
        loc, moff, msfo, colors, alphas, coef, bbox, P);

    const int block = 256;
    const int grid = (total_pix + block - 1) / block;  // ~= numTiles for 16x16
    const size_t lds = (size_t)P * 8 * sizeof(float);
    points_tiled<<<grid, block, lds, stream>>>(Hp, Wp, coef, bbox, out, P);
}